// Round 5
// baseline (121.760 us; speedup 1.0000x reference)
//
#include <hip/hip_runtime.h>
#include <hip/hip_bf16.h>

// out[b][n] = x[b][n] * |W[n][n]|   (BATCH=65536, N=1024, f32)
// v5: single kernel. 8 rows per block (8192 blocks), diag loaded directly
// from W (scattered, L2-resident, hidden under HBM loads), 8 independent
// nontemporal float4 streams per thread.

#define N_COLS 1024
#define BLOCK 256
#define ROWS_PER_BLOCK 8

typedef float v4f __attribute__((ext_vector_type(4)));

__global__ __launch_bounds__(BLOCK) void diag_scale_kernel(
    const float* __restrict__ x,
    const float* __restrict__ W,
    float* __restrict__ out)
{
    const int t = threadIdx.x;          // f4 column 0..255
    const int c0 = t * 4;

    const int row_f4 = N_COLS / 4;      // 256
    const size_t base = (size_t)blockIdx.x * (ROWS_PER_BLOCK * row_f4) + t;

    const v4f* __restrict__ xv = reinterpret_cast<const v4f*>(x);
    v4f* __restrict__ ov = reinterpret_cast<v4f*>(out);

    // Issue the 8 HBM row loads first so they're in flight while the
    // scattered diag loads resolve from L2.
    v4f r0 = __builtin_nontemporal_load(xv + base);
    v4f r1 = __builtin_nontemporal_load(xv + base + 1 * row_f4);
    v4f r2 = __builtin_nontemporal_load(xv + base + 2 * row_f4);
    v4f r3 = __builtin_nontemporal_load(xv + base + 3 * row_f4);
    v4f r4 = __builtin_nontemporal_load(xv + base + 4 * row_f4);
    v4f r5 = __builtin_nontemporal_load(xv + base + 5 * row_f4);
    v4f r6 = __builtin_nontemporal_load(xv + base + 6 * row_f4);
    v4f r7 = __builtin_nontemporal_load(xv + base + 7 * row_f4);

    // Diagonal: W[c][c] at flat c*1025, one cache line each -> L2-resident
    // after the first few blocks. Plain (cached) loads on purpose.
    v4f w;
    w.x = fabsf(W[(size_t)(c0 + 0) * (N_COLS + 1)]);
    w.y = fabsf(W[(size_t)(c0 + 1) * (N_COLS + 1)]);
    w.z = fabsf(W[(size_t)(c0 + 2) * (N_COLS + 1)]);
    w.w = fabsf(W[(size_t)(c0 + 3) * (N_COLS + 1)]);

    r0 *= w; r1 *= w; r2 *= w; r3 *= w;
    r4 *= w; r5 *= w; r6 *= w; r7 *= w;

    __builtin_nontemporal_store(r0, ov + base);
    __builtin_nontemporal_store(r1, ov + base + 1 * row_f4);
    __builtin_nontemporal_store(r2, ov + base + 2 * row_f4);
    __builtin_nontemporal_store(r3, ov + base + 3 * row_f4);
    __builtin_nontemporal_store(r4, ov + base + 4 * row_f4);
    __builtin_nontemporal_store(r5, ov + base + 5 * row_f4);
    __builtin_nontemporal_store(r6, ov + base + 6 * row_f4);
    __builtin_nontemporal_store(r7, ov + base + 7 * row_f4);
}

extern "C" void kernel_launch(void* const* d_in, const int* in_sizes, int n_in,
                              void* d_out, int out_size, void* d_ws, size_t ws_size,
                              hipStream_t stream)
{
    const float* x = (const float*)d_in[0];   // [BATCH, N]
    const float* W = (const float*)d_in[1];   // [N, N]
    float* out = (float*)d_out;               // [BATCH, N]

    const int rows = in_sizes[0] / N_COLS;    // 65536
    const int grid = rows / ROWS_PER_BLOCK;   // 8192

    diag_scale_kernel<<<grid, BLOCK, 0, stream>>>(x, W, out);
}

// Round 6
// 93.101 us; speedup vs baseline: 1.3078x; 1.3078x over previous
//
#include <hip/hip_runtime.h>
#include <hip/hip_bf16.h>

// out[b][n] = x[b][n] * |W[n][n]|   (BATCH=65536, N=1024, f32)
// v6: v4 structure (scatter diag ONCE into ws, main kernel reads ws
// coalesced) + parallel gather (4 blocks, 1 elem/thread) + 8 rows/block
// main kernel with 8 independent nontemporal float4 streams.

#define N_COLS 1024
#define BLOCK 256
#define ROWS_PER_BLOCK 8

typedef float v4f __attribute__((ext_vector_type(4)));

__global__ __launch_bounds__(BLOCK) void gather_diag_kernel(
    const float* __restrict__ W,
    float* __restrict__ ws)
{
    const int c = blockIdx.x * BLOCK + threadIdx.x;   // 0..1023, one col each
    ws[c] = fabsf(W[(size_t)c * (N_COLS + 1)]);
}

__global__ __launch_bounds__(BLOCK) void diag_scale_kernel(
    const float* __restrict__ x,
    const float* __restrict__ ws,   // |diag(W)|, 1024 floats, L2-resident
    float* __restrict__ out)
{
    const int t = threadIdx.x;                          // f4 column 0..255
    const v4f w = reinterpret_cast<const v4f*>(ws)[t];  // coalesced, cached

    const int row_f4 = N_COLS / 4;                      // 256
    const size_t base = (size_t)blockIdx.x * (ROWS_PER_BLOCK * row_f4) + t;

    const v4f* __restrict__ xv = reinterpret_cast<const v4f*>(x);
    v4f* __restrict__ ov = reinterpret_cast<v4f*>(out);

    // 8 independent loads in flight, then 8 stores. Same w for all rows
    // (thread t owns f4-column t of each consecutive row).
    v4f r0 = __builtin_nontemporal_load(xv + base);
    v4f r1 = __builtin_nontemporal_load(xv + base + 1 * row_f4);
    v4f r2 = __builtin_nontemporal_load(xv + base + 2 * row_f4);
    v4f r3 = __builtin_nontemporal_load(xv + base + 3 * row_f4);
    v4f r4 = __builtin_nontemporal_load(xv + base + 4 * row_f4);
    v4f r5 = __builtin_nontemporal_load(xv + base + 5 * row_f4);
    v4f r6 = __builtin_nontemporal_load(xv + base + 6 * row_f4);
    v4f r7 = __builtin_nontemporal_load(xv + base + 7 * row_f4);

    r0 *= w; r1 *= w; r2 *= w; r3 *= w;
    r4 *= w; r5 *= w; r6 *= w; r7 *= w;

    __builtin_nontemporal_store(r0, ov + base);
    __builtin_nontemporal_store(r1, ov + base + 1 * row_f4);
    __builtin_nontemporal_store(r2, ov + base + 2 * row_f4);
    __builtin_nontemporal_store(r3, ov + base + 3 * row_f4);
    __builtin_nontemporal_store(r4, ov + base + 4 * row_f4);
    __builtin_nontemporal_store(r5, ov + base + 5 * row_f4);
    __builtin_nontemporal_store(r6, ov + base + 6 * row_f4);
    __builtin_nontemporal_store(r7, ov + base + 7 * row_f4);
}

extern "C" void kernel_launch(void* const* d_in, const int* in_sizes, int n_in,
                              void* d_out, int out_size, void* d_ws, size_t ws_size,
                              hipStream_t stream)
{
    const float* x = (const float*)d_in[0];   // [BATCH, N]
    const float* W = (const float*)d_in[1];   // [N, N]
    float* out = (float*)d_out;               // [BATCH, N]
    float* ws = (float*)d_ws;                 // >= 4 KB scratch

    const int rows = in_sizes[0] / N_COLS;    // 65536
    const int grid = rows / ROWS_PER_BLOCK;   // 8192

    gather_diag_kernel<<<N_COLS / BLOCK, BLOCK, 0, stream>>>(W, ws);
    diag_scale_kernel<<<grid, BLOCK, 0, stream>>>(x, ws, out);
}